// Round 7
// baseline (27167.575 us; speedup 1.0000x reference)
//
#include <hip/hip_runtime.h>
#include <hip/hip_bf16.h>

#define VV 30000
#define HH 512
#define NC 9
#define BB 128
#define TT 256
#define GG 2048
#define TB (TT*BB)

using short8 = __attribute__((ext_vector_type(8))) short;
using f32x4  = __attribute__((ext_vector_type(4))) float;

__device__ inline float bf2f(unsigned short u){
    union { unsigned int i; float f; } v; v.i = ((unsigned int)u) << 16; return v.f;
}
__device__ inline unsigned short f2bf(float f){
    union { unsigned int i; float f; } v; v.f = f;
    unsigned int x = v.i;
    unsigned int r = (x + 0x7fffu + ((x >> 16) & 1u)) >> 16;
    return (unsigned short)r;
}
__device__ inline float sigm(float x){
    if (x >= 0.f){ return 1.f / (1.f + __expf(-x)); }
    float e = __expf(x); return e / (1.f + e);
}
__device__ inline float tanh_f(float x){
    float ax = fabsf(x);
    float e = __expf(-2.f * ax);
    float t = (1.f - e) / (1.f + e);
    return copysignf(t, x);
}

// ---------------- weight cast fp32 -> bf16 ----------------
__global__ void castbf(const float* __restrict__ in, unsigned short* __restrict__ out, int n){
    int i = blockIdx.x * blockDim.x + threadIdx.x;
    if (i < n) out[i] = f2bf(in[i]);
}

// ---------------- embedding + renorm -> xs bf16 [T*B][H] ----------------
__global__ __launch_bounds__(256) void embed_k(const int* __restrict__ x,
                                               const float* __restrict__ embed,
                                               unsigned short* __restrict__ xs){
    int wid  = (int)((blockIdx.x * blockDim.x + threadIdx.x) >> 6);
    int lane = threadIdx.x & 63;
    if (wid >= TB) return;
    int t = wid >> 7, b = wid & 127;
    int tok = x[b * TT + t];
    const float4* e = (const float4*)(embed + (size_t)tok * HH);
    float4 v0 = e[lane], v1 = e[lane + 64];
    float ss = v0.x*v0.x + v0.y*v0.y + v0.z*v0.z + v0.w*v0.w
             + v1.x*v1.x + v1.y*v1.y + v1.z*v1.z + v1.w*v1.w;
    #pragma unroll
    for (int off = 32; off > 0; off >>= 1) ss += __shfl_xor(ss, off, 64);
    float nrm = sqrtf(ss);
    float sc = (nrm > 1.f) ? 1.f / (nrm + 1e-7f) : 1.f;
    unsigned short* dst = xs + (size_t)wid * HH;
    ushort4 o0, o1;
    o0.x = f2bf(v0.x * sc); o0.y = f2bf(v0.y * sc); o0.z = f2bf(v0.z * sc); o0.w = f2bf(v0.w * sc);
    o1.x = f2bf(v1.x * sc); o1.y = f2bf(v1.y * sc); o1.z = f2bf(v1.z * sc); o1.w = f2bf(v1.w * sc);
    ((ushort4*)dst)[lane]      = o0;
    ((ushort4*)dst)[lane + 64] = o1;
}

// ---------------- bf16 GEMM (both dirs via blockIdx.z): C = A@W^T + bias ----------------
__global__ __launch_bounds__(256) void gemm2(const unsigned short* __restrict__ A0,
                                             const unsigned short* __restrict__ A1,
                                             const unsigned short* __restrict__ Wb_,
                                             const float* __restrict__ bias,
                                             unsigned short* __restrict__ Cout,
                                             int K, int CH){
    const int dz = blockIdx.z;
    const unsigned short* A  = dz ? A1 : A0;
    const unsigned short* W  = Wb_ + (size_t)dz * GG * K;
    const float*          bd = bias + dz * GG;
    unsigned short*       C  = Cout + (size_t)dz * CH * BB * GG;

    int lane = threadIdx.x & 63;
    int wv   = threadIdx.x >> 6;
    int m0   = blockIdx.x * 128 + (wv >> 1) * 64;
    int n0   = blockIdx.y * 128 + (wv & 1) * 64;
    int l15  = lane & 15, quad = lane >> 4;

    f32x4 acc[4][4];
    #pragma unroll
    for (int i = 0; i < 4; i++)
        #pragma unroll
        for (int j = 0; j < 4; j++){ acc[i][j][0]=0.f; acc[i][j][1]=0.f; acc[i][j][2]=0.f; acc[i][j][3]=0.f; }

    const unsigned short* Ab = A + (size_t)(m0 + l15) * K + quad * 8;
    const unsigned short* Wp = W + (size_t)(n0 + l15) * K + quad * 8;

    for (int kk = 0; kk < K; kk += 32){
        short8 a[4], bfr[4];
        #pragma unroll
        for (int i = 0; i < 4; i++) a[i]   = *(const short8*)(Ab + (size_t)i * 16 * K + kk);
        #pragma unroll
        for (int j = 0; j < 4; j++) bfr[j] = *(const short8*)(Wp + (size_t)j * 16 * K + kk);
        #pragma unroll
        for (int i = 0; i < 4; i++)
            #pragma unroll
            for (int j = 0; j < 4; j++)
                acc[i][j] = __builtin_amdgcn_mfma_f32_16x16x32_bf16(a[i], bfr[j], acc[i][j], 0, 0, 0);
    }

    #pragma unroll
    for (int i = 0; i < 4; i++){
        #pragma unroll
        for (int j = 0; j < 4; j++){
            int n = n0 + j * 16 + l15;
            float bn = bd[n];
            #pragma unroll
            for (int r = 0; r < 4; r++){
                int m = m0 + i * 16 + quad * 4 + r;
                C[(size_t)m * GG + n] = f2bf(acc[i][j][r] + bn);
            }
        }
    }
}

// ---------------- persistent BiLSTM recurrence v3 ----------------
// grid: 32 blocks = d(2) x jc(8) x mh(2); block 256 = 4 waves.
// Each block: 64 batch rows (mh) x 64 hidden cols (jc) x 4 gates.
// Per step: coalesced agent-load of the 64-row h slab (64 KB) -> LDS;
// wave w = m-tile w, 16 n-tiles (4 gates x 4 col-chunks) -> every lane holds
// all 4 gates of its 16 cells -> register-resident gate fusion, cstate in
// 16 VGPRs/lane for the whole dispatch. W_hh streams from L2 (plain cached;
// no fences anywhere). hs_out / fused emissions happen AFTER the flag store
// (hidden under the barrier poll). Barrier: 8 flags per (d,mh) group.
__global__ __launch_bounds__(256) void lstm_seq(const unsigned short* __restrict__ preC, // [2][CH][128][2048]
                                                const unsigned short* __restrict__ whh,  // [2][2048][512]
                                                unsigned short* __restrict__ hA,         // [2][128][512]
                                                unsigned short* __restrict__ hB,
                                                float* __restrict__ cstate,              // [2][128][512]
                                                unsigned short* __restrict__ hs_out,     // [TB][1024] (layer0)
                                                const float* __restrict__ cw,            // [9][1024] (layer1) or null
                                                float* __restrict__ em,                  // [T*B][9]  (layer1)
                                                int t0, int nsteps, int CH,
                                                unsigned int* __restrict__ bar){
    __shared__ unsigned short hslab[64][520];   // 66.6 KB (+8 pad: spreads banks)
    __shared__ float hrowf[64 * 68];            // 17.4 KB (layer-1 emission staging)
    __shared__ float cw_s[9 * 68];              //  2.4 KB

    const int tid  = threadIdx.x;
    const int lane = tid & 63;
    const int wv   = tid >> 6;
    const int l15  = lane & 15, quad = lane >> 4;
    const int bx   = blockIdx.x;
    const int d    = bx >> 4;
    const int jc   = (bx >> 1) & 7;
    const int mh   = bx & 1;
    const int m0   = mh * 64;
    const int jb   = jc * 64;
    const int grp  = d * 2 + mh;

    if (cw != nullptr){
        for (int i = tid; i < 9 * 64; i += 256){
            int c = i >> 6, k = i & 63;
            cw_s[c * 68 + k] = cw[(size_t)c * 1024 + d * 512 + jb + k];
        }
    }

    // ---- cstate -> registers (held for all nsteps) ----
    float csreg[16];
    #pragma unroll
    for (int rr = 0; rr < 4; rr++){
        const int gm = m0 + wv * 16 + quad * 4 + rr;
        #pragma unroll
        for (int cc = 0; cc < 4; cc++)
            csreg[rr * 4 + cc] = cstate[((size_t)d * BB + gm) * HH + jb + cc * 16 + l15];
    }
    __syncthreads();

    const size_t hdoff = (size_t)d * BB * HH;
    const unsigned short* wb = whh + (size_t)d * GG * HH;

    for (int ls = 0; ls < nsteps; ls++){
        const int tt   = t0 + ls;
        const int time = d ? (TT - 1 - tt) : tt;
        const int slot = time & (CH - 1);
        const unsigned short* srcB = ((tt & 1) ? hB : hA) + hdoff;
        unsigned short*       dstB = ((tt & 1) ? hA : hB) + hdoff;

        // ---- coalesced slab load: rows m0..m0+63, all 512 cols (64 KB) ----
        {
            const unsigned long long* srcq = (const unsigned long long*)(srcB + (size_t)m0 * HH);
            #pragma unroll
            for (int it = 0; it < 32; it++){
                int ci  = it * 256 + tid;        // 0..8191
                int row = ci >> 7, cu = ci & 127;
                unsigned long long v = __hip_atomic_load(srcq + row * 128 + cu,
                                                         __ATOMIC_RELAXED, __HIP_MEMORY_SCOPE_AGENT);
                *(unsigned long long*)&hslab[row][cu * 4] = v;
            }
        }
        __syncthreads();

        // ---- MFMA: wave = m-tile wv; 16 n-tiles = gate(4) x col-chunk(4) ----
        f32x4 acc[16];
        #pragma unroll
        for (int nt = 0; nt < 16; nt++){ acc[nt][0]=0.f; acc[nt][1]=0.f; acc[nt][2]=0.f; acc[nt][3]=0.f; }

        #pragma unroll 1
        for (int kk = 0; kk < 16; kk++){
            short8 a = *(const short8*)&hslab[wv * 16 + l15][kk * 32 + quad * 8];
            #pragma unroll
            for (int nt = 0; nt < 16; nt++){
                const int nrow = (nt >> 2) * 512 + jb + (nt & 3) * 16 + l15;
                short8 b = *(const short8*)(wb + (size_t)nrow * HH + kk * 32 + quad * 8);
                acc[nt] = __builtin_amdgcn_mfma_f32_16x16x32_bf16(a, b, acc[nt], 0, 0, 0);
            }
        }

        // ---- register-resident gate fusion; agent h stores ----
        unsigned short hbl[16];
        #pragma unroll
        for (int rr = 0; rr < 4; rr++){
            const int lr = wv * 16 + quad * 4 + rr;
            const int gm = m0 + lr;
            const unsigned short* pr = preC + (((size_t)(d * CH + slot)) * BB + gm) * GG + jb;
            #pragma unroll
            for (int cc = 0; cc < 4; cc++){
                const int lc = cc * 16 + l15;
                const float zi = acc[0 * 4 + cc][rr] + bf2f(pr[0 * 512 + lc]);
                const float zf = acc[1 * 4 + cc][rr] + bf2f(pr[1 * 512 + lc]);
                const float zg = acc[2 * 4 + cc][rr] + bf2f(pr[2 * 512 + lc]);
                const float zo = acc[3 * 4 + cc][rr] + bf2f(pr[3 * 512 + lc]);
                float cs = csreg[rr * 4 + cc];
                cs = sigm(zf) * cs + sigm(zi) * tanh_f(zg);
                csreg[rr * 4 + cc] = cs;
                const float hf = sigm(zo) * tanh_f(cs);
                const unsigned short hb = f2bf(hf);
                hbl[rr * 4 + cc] = hb;
                __hip_atomic_store(dstB + (size_t)gm * HH + jb + lc, hb,
                                   __ATOMIC_RELAXED, __HIP_MEMORY_SCOPE_AGENT);
                if (cw != nullptr) hrowf[lr * 68 + lc] = hf;
            }
        }

        // ---- barrier arm: drain h stores, publish flag ----
        __syncthreads();
        if (tid == 0)
            __hip_atomic_store(&bar[grp * 64 + jc], (unsigned int)(ls + 1),
                               __ATOMIC_RELAXED, __HIP_MEMORY_SCOPE_AGENT);

        // ---- off-critical-path work (hidden under the poll) ----
        if (cw == nullptr){
            #pragma unroll
            for (int rr = 0; rr < 4; rr++){
                const int gm = m0 + wv * 16 + quad * 4 + rr;
                #pragma unroll
                for (int cc = 0; cc < 4; cc++)
                    hs_out[((size_t)time * BB + gm) * (2 * HH) + d * HH + jb + cc * 16 + l15] = hbl[rr * 4 + cc];
            }
        } else {
            const int row = tid >> 2, part = tid & 3;
            const int gm2 = m0 + row;
            float p[NC];
            #pragma unroll
            for (int c = 0; c < NC; c++){
                float s = 0.f;
                #pragma unroll
                for (int k = 0; k < 16; k++)
                    s += hrowf[row * 68 + part * 16 + k] * cw_s[c * 68 + part * 16 + k];
                p[c] = s;
            }
            #pragma unroll
            for (int c = 0; c < NC; c++){
                p[c] += __shfl_xor(p[c], 1, 64);
                p[c] += __shfl_xor(p[c], 2, 64);
            }
            if (part == 0){
                float* emr = em + ((size_t)time * BB + gm2) * NC;
                #pragma unroll
                for (int c = 0; c < NC; c++) atomicAdd(emr + c, p[c]);
            }
        }

        // ---- poll the group's 8 flags ----
        if (ls + 1 < nsteps){
            if (tid < 64){
                const unsigned int tgt = (unsigned int)(ls + 1);
                const unsigned int* fl = bar + grp * 64 + (tid & 7);
                while (__hip_atomic_load(fl, __ATOMIC_RELAXED, __HIP_MEMORY_SCOPE_AGENT) < tgt)
                    __builtin_amdgcn_s_sleep(1);
            }
            __syncthreads();
            __builtin_amdgcn_fence(__ATOMIC_ACQUIRE, "workgroup"); // ordering only
        }
    }

    // ---- cstate registers -> global (plain; flushed at dispatch end) ----
    #pragma unroll
    for (int rr = 0; rr < 4; rr++){
        const int gm = m0 + wv * 16 + quad * 4 + rr;
        #pragma unroll
        for (int cc = 0; cc < 4; cc++)
            cstate[((size_t)d * BB + gm) * HH + jb + cc * 16 + l15] = csreg[rr * 4 + cc];
    }
}

// ---------------- em init: em[t,b,c] = cls_b[c] ----------------
__global__ void eminit(const float* __restrict__ cb, float* __restrict__ em){
    int i = blockIdx.x * blockDim.x + threadIdx.x;
    if (i < TB * NC) em[i] = cb[i % NC];
}

// ---------------- CRF per-sequence ----------------
__global__ __launch_bounds__(64) void crf_k(const int* __restrict__ y,
                                            const float* __restrict__ em,
                                            const float* __restrict__ cstart,
                                            const float* __restrict__ cend,
                                            const float* __restrict__ ctr,
                                            float* __restrict__ llh){
    int b = blockIdx.x;
    int lane = threadIdx.x;

    float sp = 0.f; int cnt = 0;
    for (int t = lane; t < TT; t += 64){
        int yt = y[b * TT + t];
        bool mk = (yt > -1);
        cnt += mk ? 1 : 0;
        if (t >= 1 && mk){
            int yp  = y[b * TT + t - 1];
            int tag  = yt > 0 ? yt : 0;
            int tagp = yp > 0 ? yp : 0;
            sp += ctr[tagp * NC + tag] + em[((size_t)t * BB + b) * NC + tag];
        }
    }
    #pragma unroll
    for (int off = 32; off > 0; off >>= 1){
        sp  += __shfl_xor(sp, off, 64);
        cnt += __shfl_xor(cnt, off, 64);
    }

    float trc[NC];
    #pragma unroll
    for (int cc2 = 0; cc2 < NC; cc2++) trc[cc2] = 0.f;
    if (lane < NC){
        #pragma unroll
        for (int cc2 = 0; cc2 < NC; cc2++) trc[cc2] = ctr[cc2 * NC + lane];
    }
    float alpha = -1e30f;
    if (lane < NC) alpha = cstart[lane] + em[(size_t)b * NC + lane];

    for (int t = 1; t < TT; t++){
        int yt = y[b * TT + t];
        bool mk = (yt > -1);
        float e = (lane < NC) ? em[((size_t)t * BB + b) * NC + lane] : 0.f;
        float v[NC]; float mx = -1e30f;
        #pragma unroll
        for (int cc2 = 0; cc2 < NC; cc2++){
            float ac = __shfl(alpha, cc2, 64);
            v[cc2] = ac + trc[cc2];
            mx = fmaxf(mx, v[cc2]);
        }
        float s = 0.f;
        #pragma unroll
        for (int cc2 = 0; cc2 < NC; cc2++) s += __expf(v[cc2] - mx);
        float nxt = mx + __logf(s) + e;
        if (mk && lane < NC) alpha = nxt;
    }

    float val = (lane < NC) ? (alpha + cend[lane]) : -1e30f;
    float mx = -1e30f;
    #pragma unroll
    for (int cc2 = 0; cc2 < NC; cc2++) mx = fmaxf(mx, __shfl(val, cc2, 64));
    float s = 0.f;
    #pragma unroll
    for (int cc2 = 0; cc2 < NC; cc2++) s += __expf(__shfl(val, cc2, 64) - mx);
    float denom = mx + __logf(s);

    if (lane == 0){
        int y0 = y[b * TT];
        int tag0 = y0 > 0 ? y0 : 0;
        int se = cnt - 1;
        if (se < 0) se = 0;
        int yl = y[b * TT + se];
        int tagl = yl > 0 ? yl : 0;
        float score = sp + cstart[tag0] + em[(size_t)b * NC + tag0] + cend[tagl];
        llh[b] = score - denom;
    }
}

__global__ void final_k(const float* __restrict__ llh, float* __restrict__ out){
    __shared__ float sm[128];
    int i = threadIdx.x;
    sm[i] = llh[i];
    __syncthreads();
    for (int s = 64; s > 0; s >>= 1){
        if (i < s) sm[i] += sm[i + s];
        __syncthreads();
    }
    if (i == 0) out[0] = -sm[0] / 128.f;
}

__global__ void sentinel_k(float* out, float v){ out[0] = v; }

extern "C" void kernel_launch(void* const* d_in, const int* in_sizes, int n_in,
                              void* d_out, int out_size, void* d_ws, size_t ws_size,
                              hipStream_t stream) {
    const int*   x     = (const int*)d_in[0];
    const int*   y     = (const int*)d_in[1];
    const float* embed = (const float*)d_in[2];
    const float* wih0  = (const float*)d_in[3];
    const float* whh0  = (const float*)d_in[4];
    const float* b0    = (const float*)d_in[5];
    const float* wih1  = (const float*)d_in[6];
    const float* whh1  = (const float*)d_in[7];
    const float* b1    = (const float*)d_in[8];
    const float* clsw  = (const float*)d_in[9];
    const float* clsb  = (const float*)d_in[10];
    const float* cst   = (const float*)d_in[11];
    const float* cen   = (const float*)d_in[12];
    const float* ctr   = (const float*)d_in[13];
    float* out = (float*)d_out;

    const size_t sz_w0   = (size_t)2 * GG * HH * 2;
    const size_t sz_w1   = (size_t)2 * GG * 1024 * 2;
    const size_t sz_xs   = (size_t)TB * HH * 2;
    const size_t sz_hs0  = (size_t)TB * 1024 * 2;
    const size_t sz_h    = (size_t)2 * BB * HH * 2;
    const size_t sz_c    = (size_t)2 * BB * HH * 4;
    const size_t sz_emis = (size_t)TB * NC * 4;
    const size_t sz_llh  = (size_t)BB * 4;
    const size_t sz_bar  = 1024;
    auto rup = [](size_t v){ return (v + 255) & ~(size_t)255; };
    size_t fixed = rup(sz_w0) * 3 + rup(sz_w1) + rup(sz_xs) + rup(sz_hs0)
                 + rup(sz_h) * 2 + rup(sz_c) + rup(sz_emis) + rup(sz_llh) + rup(sz_bar);

    const int cands[7] = {256, 128, 64, 32, 16, 8, 4};
    int CH = 0;
    for (int i = 0; i < 7; i++){
        size_t need = fixed + rup((size_t)2 * cands[i] * BB * GG * 2);
        if (need <= ws_size){ CH = cands[i]; break; }
    }
    if (CH == 0){
        sentinel_k<<<1, 1, 0, stream>>>(out, -(float)(ws_size >> 20));
        return;
    }

    char* ws = (char*)d_ws;
    size_t off = 0;
    auto alloc = [&](size_t bytes) -> void* {
        void* p = (void*)(ws + off);
        off += (bytes + 255) & ~(size_t)255;
        return p;
    };
    unsigned short* wih0b = (unsigned short*)alloc(sz_w0);
    unsigned short* whh0b = (unsigned short*)alloc(sz_w0);
    unsigned short* whh1b = (unsigned short*)alloc(sz_w0);
    unsigned short* wih1b = (unsigned short*)alloc(sz_w1);
    unsigned short* xs    = (unsigned short*)alloc(sz_xs);
    unsigned short* hs0   = (unsigned short*)alloc(sz_hs0);
    unsigned short* hA    = (unsigned short*)alloc(sz_h);
    unsigned short* hB    = (unsigned short*)alloc(sz_h);
    float*          cbuf  = (float*)alloc(sz_c);
    float*          emis  = (float*)alloc(sz_emis);
    float*          llh   = (float*)alloc(sz_llh);
    unsigned int*   bar   = (unsigned int*)alloc(sz_bar);
    unsigned short* preC  = (unsigned short*)alloc((size_t)2 * CH * BB * GG * 2);

    castbf<<<(2 * GG * HH + 255) / 256, 256, 0, stream>>>(wih0, wih0b, 2 * GG * HH);
    castbf<<<(2 * GG * HH + 255) / 256, 256, 0, stream>>>(whh0, whh0b, 2 * GG * HH);
    castbf<<<(2 * GG * 1024 + 255) / 256, 256, 0, stream>>>(wih1, wih1b, 2 * GG * 1024);
    castbf<<<(2 * GG * HH + 255) / 256, 256, 0, stream>>>(whh1, whh1b, 2 * GG * HH);

    embed_k<<<TB / 4, 256, 0, stream>>>(x, embed, xs);

    const int nch = TT / CH;

    // ---------- layer 0 (writes hs0) ----------
    (void)hipMemsetAsync(hA, 0, sz_h, stream);
    (void)hipMemsetAsync(cbuf, 0, sz_c, stream);
    for (int c = 0; c < nch; c++){
        int t0f = c * CH;
        int t0b = TT - (c + 1) * CH;
        gemm2<<<dim3(CH, GG / 128, 2), 256, 0, stream>>>(
            xs + (size_t)t0f * BB * HH, xs + (size_t)t0b * BB * HH,
            wih0b, b0, preC, HH, CH);
        (void)hipMemsetAsync(bar, 0, sz_bar, stream);
        lstm_seq<<<32, 256, 0, stream>>>(preC, whh0b, hA, hB, cbuf, hs0,
                                         nullptr, emis, c * CH, CH, CH, bar);
    }

    // ---------- emissions init ----------
    eminit<<<(TB * NC + 255) / 256, 256, 0, stream>>>(clsb, emis);

    // ---------- layer 1 (fused emissions, no hs1) ----------
    (void)hipMemsetAsync(hA, 0, sz_h, stream);
    (void)hipMemsetAsync(cbuf, 0, sz_c, stream);
    for (int c = 0; c < nch; c++){
        int t0f = c * CH;
        int t0b = TT - (c + 1) * CH;
        gemm2<<<dim3(CH, GG / 128, 2), 256, 0, stream>>>(
            hs0 + (size_t)t0f * BB * 1024, hs0 + (size_t)t0b * BB * 1024,
            wih1b, b1, preC, 1024, CH);
        (void)hipMemsetAsync(bar, 0, sz_bar, stream);
        lstm_seq<<<32, 256, 0, stream>>>(preC, whh1b, hA, hB, cbuf, hs0,
                                         clsw, emis, c * CH, CH, CH, bar);
    }

    crf_k<<<BB, 64, 0, stream>>>(y, emis, cst, cen, ctr, llh);
    final_k<<<1, 128, 0, stream>>>(llh, out);
}

// Round 8
// 9090.411 us; speedup vs baseline: 2.9886x; 2.9886x over previous
//
#include <hip/hip_runtime.h>
#include <hip/hip_bf16.h>

#define VV 30000
#define HH 512
#define NC 9
#define BB 128
#define TT 256
#define GG 2048
#define TB (TT*BB)

using short8 = __attribute__((ext_vector_type(8))) short;
using f32x4  = __attribute__((ext_vector_type(4))) float;

__device__ inline float bf2f(unsigned short u){
    union { unsigned int i; float f; } v; v.i = ((unsigned int)u) << 16; return v.f;
}
__device__ inline unsigned short f2bf(float f){
    union { unsigned int i; float f; } v; v.f = f;
    unsigned int x = v.i;
    unsigned int r = (x + 0x7fffu + ((x >> 16) & 1u)) >> 16;
    return (unsigned short)r;
}
__device__ inline float sigm(float x){
    if (x >= 0.f){ return 1.f / (1.f + __expf(-x)); }
    float e = __expf(x); return e / (1.f + e);
}
__device__ inline float tanh_f(float x){
    float ax = fabsf(x);
    float e = __expf(-2.f * ax);
    float t = (1.f - e) / (1.f + e);
    return copysignf(t, x);
}

// ---------------- weight cast fp32 -> bf16 ----------------
__global__ void castbf(const float* __restrict__ in, unsigned short* __restrict__ out, int n){
    int i = blockIdx.x * blockDim.x + threadIdx.x;
    if (i < n) out[i] = f2bf(in[i]);
}

// ---------------- embedding + renorm -> xs bf16 [T*B][H] ----------------
__global__ __launch_bounds__(256) void embed_k(const int* __restrict__ x,
                                               const float* __restrict__ embed,
                                               unsigned short* __restrict__ xs){
    int wid  = (int)((blockIdx.x * blockDim.x + threadIdx.x) >> 6);
    int lane = threadIdx.x & 63;
    if (wid >= TB) return;
    int t = wid >> 7, b = wid & 127;
    int tok = x[b * TT + t];
    const float4* e = (const float4*)(embed + (size_t)tok * HH);
    float4 v0 = e[lane], v1 = e[lane + 64];
    float ss = v0.x*v0.x + v0.y*v0.y + v0.z*v0.z + v0.w*v0.w
             + v1.x*v1.x + v1.y*v1.y + v1.z*v1.z + v1.w*v1.w;
    #pragma unroll
    for (int off = 32; off > 0; off >>= 1) ss += __shfl_xor(ss, off, 64);
    float nrm = sqrtf(ss);
    float sc = (nrm > 1.f) ? 1.f / (nrm + 1e-7f) : 1.f;
    unsigned short* dst = xs + (size_t)wid * HH;
    ushort4 o0, o1;
    o0.x = f2bf(v0.x * sc); o0.y = f2bf(v0.y * sc); o0.z = f2bf(v0.z * sc); o0.w = f2bf(v0.w * sc);
    o1.x = f2bf(v1.x * sc); o1.y = f2bf(v1.y * sc); o1.z = f2bf(v1.z * sc); o1.w = f2bf(v1.w * sc);
    ((ushort4*)dst)[lane]      = o0;
    ((ushort4*)dst)[lane + 64] = o1;
}

// ---------------- bf16 GEMM (both dirs via blockIdx.z): C = A@W^T + bias ----------------
__global__ __launch_bounds__(256) void gemm2(const unsigned short* __restrict__ A0,
                                             const unsigned short* __restrict__ A1,
                                             const unsigned short* __restrict__ Wb_,
                                             const float* __restrict__ bias,
                                             unsigned short* __restrict__ Cout,
                                             int K, int CH){
    const int dz = blockIdx.z;
    const unsigned short* A  = dz ? A1 : A0;
    const unsigned short* W  = Wb_ + (size_t)dz * GG * K;
    const float*          bd = bias + dz * GG;
    unsigned short*       C  = Cout + (size_t)dz * CH * BB * GG;

    int lane = threadIdx.x & 63;
    int wv   = threadIdx.x >> 6;
    int m0   = blockIdx.x * 128 + (wv >> 1) * 64;
    int n0   = blockIdx.y * 128 + (wv & 1) * 64;
    int l15  = lane & 15, quad = lane >> 4;

    f32x4 acc[4][4];
    #pragma unroll
    for (int i = 0; i < 4; i++)
        #pragma unroll
        for (int j = 0; j < 4; j++){ acc[i][j][0]=0.f; acc[i][j][1]=0.f; acc[i][j][2]=0.f; acc[i][j][3]=0.f; }

    const unsigned short* Ab = A + (size_t)(m0 + l15) * K + quad * 8;
    const unsigned short* Wp = W + (size_t)(n0 + l15) * K + quad * 8;

    for (int kk = 0; kk < K; kk += 32){
        short8 a[4], bfr[4];
        #pragma unroll
        for (int i = 0; i < 4; i++) a[i]   = *(const short8*)(Ab + (size_t)i * 16 * K + kk);
        #pragma unroll
        for (int j = 0; j < 4; j++) bfr[j] = *(const short8*)(Wp + (size_t)j * 16 * K + kk);
        #pragma unroll
        for (int i = 0; i < 4; i++)
            #pragma unroll
            for (int j = 0; j < 4; j++)
                acc[i][j] = __builtin_amdgcn_mfma_f32_16x16x32_bf16(a[i], bfr[j], acc[i][j], 0, 0, 0);
    }

    #pragma unroll
    for (int i = 0; i < 4; i++){
        #pragma unroll
        for (int j = 0; j < 4; j++){
            int n = n0 + j * 16 + l15;
            float bn = bd[n];
            #pragma unroll
            for (int r = 0; r < 4; r++){
                int m = m0 + i * 16 + quad * 4 + r;
                C[(size_t)m * GG + n] = f2bf(acc[i][j][r] + bn);
            }
        }
    }
}

// ---------------- persistent BiLSTM recurrence v4 ----------------
// grid: 128 blocks; grp = bx&3 -> (d, mh); jc = bx>>2 (16 hidden cols).
// grp-major indexing puts each (d,mh) group's 32 blocks on ~2 XCDs (heuristic).
// W_hh slice in LDS (staged once). h exchanged in BLOCKED layout
// h[d][mh][jc][64row][16col]: producer tile = contiguous 2KB (256 coalesced
// 8B agent stores), consumer slab = contiguous 64KB (coalesced 8B agent
// loads -> LDS). No fences: only h/flags use agent-scope atomics; W/preC/
// cstate are plain cached. cstate in 4 VGPRs/lane for the whole dispatch.
// hs_out / fused emissions after the flag store (hidden under the poll).
__global__ __launch_bounds__(256) void lstm_seq(const unsigned short* __restrict__ preC, // [2][CH][128][2048]
                                                const unsigned short* __restrict__ whh,  // [2][2048][512]
                                                unsigned short* __restrict__ hA,         // blocked, 256KB
                                                unsigned short* __restrict__ hB,
                                                float* __restrict__ cstate,              // [2][128][512]
                                                unsigned short* __restrict__ hs_out,     // [TB][1024] (layer0)
                                                const float* __restrict__ cw,            // [9][1024] (layer1) or null
                                                float* __restrict__ em,                  // [T*B][9]  (layer1)
                                                int t0, int nsteps, int CH,
                                                unsigned int* __restrict__ bar){
    __shared__ unsigned short w_s[4][16][520];   // 66.6 KB
    __shared__ unsigned short hslab[64][520];    // 66.6 KB
    __shared__ unsigned short htile[64][20];     //  2.5 KB
    __shared__ float cw_s[NC][16];

    const int tid  = threadIdx.x;
    const int lane = tid & 63;
    const int wv   = tid >> 6;
    const int l15  = lane & 15, quad = lane >> 4;
    const int bx   = blockIdx.x;
    const int grp  = bx & 3;          // (d, mh)
    const int d    = grp >> 1;
    const int mh   = grp & 1;
    const int jc   = bx >> 2;         // 0..31
    const int m0   = mh * 64;

    // ---- stage W_hh slice into LDS (once) ----
    {
        const unsigned short* wbase = whh + (size_t)d * GG * HH;
        #pragma unroll
        for (int it = 0; it < 16; it++){
            int idx  = it * 256 + tid;
            int row  = idx >> 6;
            int col8 = idx & 63;
            int g2 = row >> 4, j2 = row & 15;
            short8 v = *(const short8*)(wbase + (size_t)(g2 * 512 + jc * 16 + j2) * HH + col8 * 8);
            *(short8*)&w_s[g2][j2][col8 * 8] = v;
        }
    }
    if (cw != nullptr && tid < NC * 16){
        int c = tid >> 4, j = tid & 15;
        cw_s[c][j] = cw[(size_t)c * 1024 + d * 512 + jc * 16 + j];
    }

    // ---- cstate -> 4 registers (held for the whole dispatch) ----
    float csreg[4];
    #pragma unroll
    for (int rr = 0; rr < 4; rr++){
        const int gm = m0 + wv * 16 + quad * 4 + rr;
        csreg[rr] = cstate[((size_t)d * BB + gm) * HH + jc * 16 + l15];
    }
    __syncthreads();

    const size_t slabElems = (size_t)32 * 64 * 16;   // per (d,mh): 32768 elems = 64 KB

    for (int ls = 0; ls < nsteps; ls++){
        const int tt   = t0 + ls;
        const int time = d ? (TT - 1 - tt) : tt;
        const int slot = time & (CH - 1);
        const unsigned short* srcB = (tt & 1) ? hB : hA;
        unsigned short*       dstB = (tt & 1) ? hA : hB;
        const unsigned long long* slab  = (const unsigned long long*)(srcB + (size_t)grp * slabElems);
        unsigned long long*       dtile = (unsigned long long*)(dstB + (size_t)grp * slabElems + (size_t)jc * 1024);

        // ---- consumer: contiguous 64KB slab -> LDS (coalesced 8B agent loads) ----
        #pragma unroll
        for (int it = 0; it < 32; it++){
            int n = it * 256 + tid;             // 8B units, 0..8191
            unsigned long long v = __hip_atomic_load(slab + n, __ATOMIC_RELAXED, __HIP_MEMORY_SCOPE_AGENT);
            int jcp = n >> 8;                   // source jc block
            int rem = n & 255;
            int row = rem >> 2;
            int c4  = (rem & 3) * 4;
            *(unsigned long long*)&hslab[row][jcp * 16 + c4] = v;
        }
        __syncthreads();

        // ---- MFMA: wave = m-subtile, 4 gate n-tiles, A & B from LDS ----
        f32x4 acc[4];
        #pragma unroll
        for (int g = 0; g < 4; g++){ acc[g][0]=0.f; acc[g][1]=0.f; acc[g][2]=0.f; acc[g][3]=0.f; }
        #pragma unroll
        for (int kk = 0; kk < 16; kk++){
            short8 a = *(const short8*)&hslab[wv * 16 + l15][kk * 32 + quad * 8];
            #pragma unroll
            for (int g = 0; g < 4; g++){
                short8 b = *(const short8*)&w_s[g][l15][kk * 32 + quad * 8];
                acc[g] = __builtin_amdgcn_mfma_f32_16x16x32_bf16(a, b, acc[g], 0, 0, 0);
            }
        }

        // ---- gate fusion: 4 cells/lane, cstate in regs ----
        #pragma unroll
        for (int rr = 0; rr < 4; rr++){
            const int lr = wv * 16 + quad * 4 + rr;
            const int gm = m0 + lr;
            const unsigned short* pr = preC + (((size_t)(d * CH + slot)) * BB + gm) * GG + jc * 16 + l15;
            const float zi = acc[0][rr] + bf2f(pr[0]);
            const float zf = acc[1][rr] + bf2f(pr[512]);
            const float zg = acc[2][rr] + bf2f(pr[1024]);
            const float zo = acc[3][rr] + bf2f(pr[1536]);
            float cs = sigm(zf) * csreg[rr] + sigm(zi) * tanh_f(zg);
            csreg[rr] = cs;
            htile[lr][l15] = f2bf(sigm(zo) * tanh_f(cs));
        }
        __syncthreads();

        // ---- producer: contiguous 2KB tile store (coalesced 8B agent stores) ----
        const int trow = tid >> 2, tc4 = (tid & 3) * 4;
        const unsigned long long hv8 = *(const unsigned long long*)&htile[trow][tc4];
        __hip_atomic_store(dtile + tid, hv8, __ATOMIC_RELAXED, __HIP_MEMORY_SCOPE_AGENT);

        __syncthreads();   // drains all threads' stores (vmcnt 0) before flag
        if (tid == 0)
            __hip_atomic_store(&bar[grp * 128 + jc], (unsigned int)(ls + 1),
                               __ATOMIC_RELAXED, __HIP_MEMORY_SCOPE_AGENT);

        // ---- off-critical-path work (hidden under the poll) ----
        if (cw == nullptr){
            *(unsigned long long*)(hs_out + ((size_t)time * BB + m0 + trow) * (2 * HH) + d * HH + jc * 16 + tc4) = hv8;
        } else {
            const int part = tid & 3;
            float hvv[4];
            #pragma unroll
            for (int k = 0; k < 4; k++) hvv[k] = bf2f(htile[trow][part * 4 + k]);
            float p[NC];
            #pragma unroll
            for (int c = 0; c < NC; c++){
                float s = 0.f;
                #pragma unroll
                for (int k = 0; k < 4; k++) s += hvv[k] * cw_s[c][part * 4 + k];
                p[c] = s;
            }
            #pragma unroll
            for (int c = 0; c < NC; c++){
                p[c] += __shfl_xor(p[c], 1, 64);
                p[c] += __shfl_xor(p[c], 2, 64);
            }
            if (part == 0){
                float* emr = em + ((size_t)time * BB + m0 + trow) * NC;
                #pragma unroll
                for (int c = 0; c < NC; c++) atomicAdd(emr + c, p[c]);
            }
        }

        // ---- poll the group's 32 flags ----
        if (ls + 1 < nsteps){
            if (tid < 32){
                const unsigned int tgt = (unsigned int)(ls + 1);
                const unsigned int* fl = bar + grp * 128 + tid;
                while (__hip_atomic_load(fl, __ATOMIC_RELAXED, __HIP_MEMORY_SCOPE_AGENT) < tgt)
                    __builtin_amdgcn_s_sleep(1);
            }
            __syncthreads();
            __builtin_amdgcn_fence(__ATOMIC_ACQUIRE, "workgroup");  // compiler ordering only
        }
    }

    // ---- cstate regs -> global ----
    #pragma unroll
    for (int rr = 0; rr < 4; rr++){
        const int gm = m0 + wv * 16 + quad * 4 + rr;
        cstate[((size_t)d * BB + gm) * HH + jc * 16 + l15] = csreg[rr];
    }
}

// ---------------- em init: em[t,b,c] = cls_b[c] ----------------
__global__ void eminit(const float* __restrict__ cb, float* __restrict__ em){
    int i = blockIdx.x * blockDim.x + threadIdx.x;
    if (i < TB * NC) em[i] = cb[i % NC];
}

// ---------------- CRF per-sequence ----------------
__global__ __launch_bounds__(64) void crf_k(const int* __restrict__ y,
                                            const float* __restrict__ em,
                                            const float* __restrict__ cstart,
                                            const float* __restrict__ cend,
                                            const float* __restrict__ ctr,
                                            float* __restrict__ llh){
    int b = blockIdx.x;
    int lane = threadIdx.x;

    float sp = 0.f; int cnt = 0;
    for (int t = lane; t < TT; t += 64){
        int yt = y[b * TT + t];
        bool mk = (yt > -1);
        cnt += mk ? 1 : 0;
        if (t >= 1 && mk){
            int yp  = y[b * TT + t - 1];
            int tag  = yt > 0 ? yt : 0;
            int tagp = yp > 0 ? yp : 0;
            sp += ctr[tagp * NC + tag] + em[((size_t)t * BB + b) * NC + tag];
        }
    }
    #pragma unroll
    for (int off = 32; off > 0; off >>= 1){
        sp  += __shfl_xor(sp, off, 64);
        cnt += __shfl_xor(cnt, off, 64);
    }

    float trc[NC];
    #pragma unroll
    for (int cc2 = 0; cc2 < NC; cc2++) trc[cc2] = 0.f;
    if (lane < NC){
        #pragma unroll
        for (int cc2 = 0; cc2 < NC; cc2++) trc[cc2] = ctr[cc2 * NC + lane];
    }
    float alpha = -1e30f;
    if (lane < NC) alpha = cstart[lane] + em[(size_t)b * NC + lane];

    for (int t = 1; t < TT; t++){
        int yt = y[b * TT + t];
        bool mk = (yt > -1);
        float e = (lane < NC) ? em[((size_t)t * BB + b) * NC + lane] : 0.f;
        float v[NC]; float mx = -1e30f;
        #pragma unroll
        for (int cc2 = 0; cc2 < NC; cc2++){
            float ac = __shfl(alpha, cc2, 64);
            v[cc2] = ac + trc[cc2];
            mx = fmaxf(mx, v[cc2]);
        }
        float s = 0.f;
        #pragma unroll
        for (int cc2 = 0; cc2 < NC; cc2++) s += __expf(v[cc2] - mx);
        float nxt = mx + __logf(s) + e;
        if (mk && lane < NC) alpha = nxt;
    }

    float val = (lane < NC) ? (alpha + cend[lane]) : -1e30f;
    float mx = -1e30f;
    #pragma unroll
    for (int cc2 = 0; cc2 < NC; cc2++) mx = fmaxf(mx, __shfl(val, cc2, 64));
    float s = 0.f;
    #pragma unroll
    for (int cc2 = 0; cc2 < NC; cc2++) s += __expf(__shfl(val, cc2, 64) - mx);
    float denom = mx + __logf(s);

    if (lane == 0){
        int y0 = y[b * TT];
        int tag0 = y0 > 0 ? y0 : 0;
        int se = cnt - 1;
        if (se < 0) se = 0;
        int yl = y[b * TT + se];
        int tagl = yl > 0 ? yl : 0;
        float score = sp + cstart[tag0] + em[(size_t)b * NC + tag0] + cend[tagl];
        llh[b] = score - denom;
    }
}

__global__ void final_k(const float* __restrict__ llh, float* __restrict__ out){
    __shared__ float sm[128];
    int i = threadIdx.x;
    sm[i] = llh[i];
    __syncthreads();
    for (int s = 64; s > 0; s >>= 1){
        if (i < s) sm[i] += sm[i + s];
        __syncthreads();
    }
    if (i == 0) out[0] = -sm[0] / 128.f;
}

__global__ void sentinel_k(float* out, float v){ out[0] = v; }

extern "C" void kernel_launch(void* const* d_in, const int* in_sizes, int n_in,
                              void* d_out, int out_size, void* d_ws, size_t ws_size,
                              hipStream_t stream) {
    const int*   x     = (const int*)d_in[0];
    const int*   y     = (const int*)d_in[1];
    const float* embed = (const float*)d_in[2];
    const float* wih0  = (const float*)d_in[3];
    const float* whh0  = (const float*)d_in[4];
    const float* b0    = (const float*)d_in[5];
    const float* wih1  = (const float*)d_in[6];
    const float* whh1  = (const float*)d_in[7];
    const float* b1    = (const float*)d_in[8];
    const float* clsw  = (const float*)d_in[9];
    const float* clsb  = (const float*)d_in[10];
    const float* cst   = (const float*)d_in[11];
    const float* cen   = (const float*)d_in[12];
    const float* ctr   = (const float*)d_in[13];
    float* out = (float*)d_out;

    const size_t sz_w0   = (size_t)2 * GG * HH * 2;
    const size_t sz_w1   = (size_t)2 * GG * 1024 * 2;
    const size_t sz_xs   = (size_t)TB * HH * 2;
    const size_t sz_hs0  = (size_t)TB * 1024 * 2;
    const size_t sz_h    = (size_t)2 * BB * HH * 2;
    const size_t sz_c    = (size_t)2 * BB * HH * 4;
    const size_t sz_emis = (size_t)TB * NC * 4;
    const size_t sz_llh  = (size_t)BB * 4;
    const size_t sz_bar  = 2048;
    auto rup = [](size_t v){ return (v + 255) & ~(size_t)255; };
    size_t fixed = rup(sz_w0) * 3 + rup(sz_w1) + rup(sz_xs) + rup(sz_hs0)
                 + rup(sz_h) * 2 + rup(sz_c) + rup(sz_emis) + rup(sz_llh) + rup(sz_bar);

    const int cands[7] = {256, 128, 64, 32, 16, 8, 4};
    int CH = 0;
    for (int i = 0; i < 7; i++){
        size_t need = fixed + rup((size_t)2 * cands[i] * BB * GG * 2);
        if (need <= ws_size){ CH = cands[i]; break; }
    }
    if (CH == 0){
        sentinel_k<<<1, 1, 0, stream>>>(out, -(float)(ws_size >> 20));
        return;
    }

    char* ws = (char*)d_ws;
    size_t off = 0;
    auto alloc = [&](size_t bytes) -> void* {
        void* p = (void*)(ws + off);
        off += (bytes + 255) & ~(size_t)255;
        return p;
    };
    unsigned short* wih0b = (unsigned short*)alloc(sz_w0);
    unsigned short* whh0b = (unsigned short*)alloc(sz_w0);
    unsigned short* whh1b = (unsigned short*)alloc(sz_w0);
    unsigned short* wih1b = (unsigned short*)alloc(sz_w1);
    unsigned short* xs    = (unsigned short*)alloc(sz_xs);
    unsigned short* hs0   = (unsigned short*)alloc(sz_hs0);
    unsigned short* hA    = (unsigned short*)alloc(sz_h);
    unsigned short* hB    = (unsigned short*)alloc(sz_h);
    float*          cbuf  = (float*)alloc(sz_c);
    float*          emis  = (float*)alloc(sz_emis);
    float*          llh   = (float*)alloc(sz_llh);
    unsigned int*   bar   = (unsigned int*)alloc(sz_bar);
    unsigned short* preC  = (unsigned short*)alloc((size_t)2 * CH * BB * GG * 2);

    castbf<<<(2 * GG * HH + 255) / 256, 256, 0, stream>>>(wih0, wih0b, 2 * GG * HH);
    castbf<<<(2 * GG * HH + 255) / 256, 256, 0, stream>>>(whh0, whh0b, 2 * GG * HH);
    castbf<<<(2 * GG * 1024 + 255) / 256, 256, 0, stream>>>(wih1, wih1b, 2 * GG * 1024);
    castbf<<<(2 * GG * HH + 255) / 256, 256, 0, stream>>>(whh1, whh1b, 2 * GG * HH);

    embed_k<<<TB / 4, 256, 0, stream>>>(x, embed, xs);

    const int nch = TT / CH;

    // ---------- layer 0 (writes hs0) ----------
    (void)hipMemsetAsync(hA, 0, sz_h, stream);
    (void)hipMemsetAsync(cbuf, 0, sz_c, stream);
    for (int c = 0; c < nch; c++){
        int t0f = c * CH;
        int t0b = TT - (c + 1) * CH;
        gemm2<<<dim3(CH, GG / 128, 2), 256, 0, stream>>>(
            xs + (size_t)t0f * BB * HH, xs + (size_t)t0b * BB * HH,
            wih0b, b0, preC, HH, CH);
        (void)hipMemsetAsync(bar, 0, sz_bar, stream);
        lstm_seq<<<128, 256, 0, stream>>>(preC, whh0b, hA, hB, cbuf, hs0,
                                          nullptr, emis, c * CH, CH, CH, bar);
    }

    // ---------- emissions init ----------
    eminit<<<(TB * NC + 255) / 256, 256, 0, stream>>>(clsb, emis);

    // ---------- layer 1 (fused emissions, no hs1) ----------
    (void)hipMemsetAsync(hA, 0, sz_h, stream);
    (void)hipMemsetAsync(cbuf, 0, sz_c, stream);
    for (int c = 0; c < nch; c++){
        int t0f = c * CH;
        int t0b = TT - (c + 1) * CH;
        gemm2<<<dim3(CH, GG / 128, 2), 256, 0, stream>>>(
            hs0 + (size_t)t0f * BB * 1024, hs0 + (size_t)t0b * BB * 1024,
            wih1b, b1, preC, 1024, CH);
        (void)hipMemsetAsync(bar, 0, sz_bar, stream);
        lstm_seq<<<128, 256, 0, stream>>>(preC, whh1b, hA, hB, cbuf, hs0,
                                          clsw, emis, c * CH, CH, CH, bar);
    }

    crf_k<<<BB, 64, 0, stream>>>(y, emis, cst, cen, ctr, llh);
    final_k<<<1, 128, 0, stream>>>(llh, out);
}